// Round 1
// baseline (1411.505 us; speedup 1.0000x reference)
//
#include <hip/hip_runtime.h>
#include <math.h>

// Problem dims (fixed by reference)
#define NLAYER 4
#define DMODEL 640
#define DINNER 1280
#define DSTATE 16
#define DTRANK 40
#define DCONV  4
#define BATCH  64
#define SEQ    30
#define MTOK   (BATCH*SEQ)      // 1920
#define NPROJ  (2*DINNER)       // 2560
#define NDBL   (DTRANK+2*DSTATE) // 72

__device__ __forceinline__ float siluf(float x) {
    return x / (1.0f + __expf(-x));
}

// h[b,v,:] = x[b,(v + SEQ - vs[b]) % SEQ, :]
__global__ void k_permute(const float* __restrict__ x, const int* __restrict__ vs,
                          float* __restrict__ h) {
    int idx = blockIdx.x * blockDim.x + threadIdx.x;
    if (idx >= MTOK * DMODEL) return;
    int d  = idx % DMODEL;
    int mv = idx / DMODEL;
    int v  = mv % SEQ;
    int b  = mv / SEQ;
    int src = (v + SEQ - vs[b]) % SEQ;
    h[idx] = x[(b * SEQ + src) * DMODEL + d];
}

// one wave per token row: xn = h * rsqrt(mean(h^2)+eps) * w
__global__ __launch_bounds__(64)
void k_rmsnorm(const float* __restrict__ h, const float* __restrict__ w,
               float* __restrict__ xn) {
    int m = blockIdx.x;
    int t = threadIdx.x;
    const float* row = h + (size_t)m * DMODEL;
    float ss = 0.f;
    for (int d = t; d < DMODEL; d += 64) { float v = row[d]; ss += v * v; }
    #pragma unroll
    for (int o = 32; o > 0; o >>= 1) ss += __shfl_xor(ss, o, 64);
    float sc = rsqrtf(ss / DMODEL + 1e-5f);
    float* out = xn + (size_t)m * DMODEL;
    for (int d = t; d < DMODEL; d += 64) out[d] = row[d] * sc * w[d];
}

// C[m,n] = sum_k A[m,lda]*W[n,k] (+ resid[m,n]); BM=BN=64, BK=16, 4x4/thread.
// Grid: (ceil(N/64), M/64). M must be multiple of 64 (1920 ok). K mult of 16.
__global__ __launch_bounds__(256)
void k_gemm(const float* __restrict__ A, int lda,
            const float* __restrict__ W,
            const float* __restrict__ resid,
            float* __restrict__ C, int N, int K) {
    __shared__ float As[16][64];
    __shared__ float Bs[16][64];
    int t  = threadIdx.x;
    int tx = t & 15, ty = t >> 4;
    int m0 = blockIdx.y * 64, n0 = blockIdx.x * 64;
    int lrow = t >> 2;          // 0..63
    int lk   = (t & 3) * 4;     // 0,4,8,12
    float c[4][4] = {{0.f}};
    for (int k0 = 0; k0 < K; k0 += 16) {
        float4 a4 = *(const float4*)(A + (size_t)(m0 + lrow) * lda + k0 + lk);
        float4 b4 = make_float4(0.f, 0.f, 0.f, 0.f);
        if (n0 + lrow < N)
            b4 = *(const float4*)(W + (size_t)(n0 + lrow) * K + k0 + lk);
        __syncthreads();
        As[lk + 0][lrow] = a4.x; As[lk + 1][lrow] = a4.y;
        As[lk + 2][lrow] = a4.z; As[lk + 3][lrow] = a4.w;
        Bs[lk + 0][lrow] = b4.x; Bs[lk + 1][lrow] = b4.y;
        Bs[lk + 2][lrow] = b4.z; Bs[lk + 3][lrow] = b4.w;
        __syncthreads();
        #pragma unroll
        for (int kk = 0; kk < 16; ++kk) {
            float4 av = *(const float4*)&As[kk][ty * 4];
            float4 bv = *(const float4*)&Bs[kk][tx * 4];
            c[0][0] += av.x * bv.x; c[0][1] += av.x * bv.y;
            c[0][2] += av.x * bv.z; c[0][3] += av.x * bv.w;
            c[1][0] += av.y * bv.x; c[1][1] += av.y * bv.y;
            c[1][2] += av.y * bv.z; c[1][3] += av.y * bv.w;
            c[2][0] += av.z * bv.x; c[2][1] += av.z * bv.y;
            c[2][2] += av.z * bv.z; c[2][3] += av.z * bv.w;
            c[3][0] += av.w * bv.x; c[3][1] += av.w * bv.y;
            c[3][2] += av.w * bv.z; c[3][3] += av.w * bv.w;
        }
    }
    #pragma unroll
    for (int i = 0; i < 4; ++i) {
        int m = m0 + ty * 4 + i;
        int n = n0 + tx * 4;
        if (n + 4 <= N) {
            float4 cv = make_float4(c[i][0], c[i][1], c[i][2], c[i][3]);
            if (resid) {
                float4 rv = *(const float4*)(resid + (size_t)m * N + n);
                cv.x += rv.x; cv.y += rv.y; cv.z += rv.z; cv.w += rv.w;
            }
            *(float4*)(C + (size_t)m * N + n) = cv;
        } else {
            for (int j = 0; j < 4; ++j) {
                if (n + j < N) {
                    float val = c[i][j];
                    if (resid) val += resid[(size_t)m * N + n + j];
                    C[(size_t)m * N + n + j] = val;
                }
            }
        }
    }
}

// causal depthwise conv over v, in place on the u half of ur (stride NPROJ), + bias, silu
__global__ void k_conv(float* __restrict__ ur, const float* __restrict__ cw,
                       const float* __restrict__ cb) {
    int idx = blockIdx.x * blockDim.x + threadIdx.x;  // b*DINNER + c
    if (idx >= BATCH * DINNER) return;
    int c = idx % DINNER;
    int b = idx / DINNER;
    float w0 = cw[c * 4 + 0], w1 = cw[c * 4 + 1], w2 = cw[c * 4 + 2], w3 = cw[c * 4 + 3];
    float bias = cb[c];
    float* base = ur + (size_t)(b * SEQ) * NPROJ + c;
    float x0 = 0.f, x1 = 0.f, x2 = 0.f;
    for (int v = 0; v < SEQ; ++v) {
        float x3 = base[(size_t)v * NPROJ];
        float o = bias + w0 * x0 + w1 * x1 + w2 * x2 + w3 * x3;
        base[(size_t)v * NPROJ] = siluf(o);
        x0 = x1; x1 = x2; x2 = x3;
    }
}

// delta[m,d] = softplus(sum_r dbl[m,r]*dtw[d,r] + dtb[d])
__global__ __launch_bounds__(256)
void k_dt(const float* __restrict__ dbl, const float* __restrict__ dtw,
          const float* __restrict__ dtb, float* __restrict__ delta) {
    __shared__ float row[DTRANK];
    int idx = blockIdx.x * 256 + threadIdx.x;
    int m = idx / DINNER;     // uniform per block (DINNER % 256 == 0)
    int d = idx % DINNER;
    if (threadIdx.x < DTRANK) row[threadIdx.x] = dbl[(size_t)m * NDBL + threadIdx.x];
    __syncthreads();
    float acc = dtb[d];
    const float* wp = dtw + (size_t)d * DTRANK;
    #pragma unroll
    for (int r = 0; r < DTRANK; ++r) acc += row[r] * wp[r];
    delta[idx] = (acc > 20.f) ? acc : log1pf(__expf(acc));
}

// selective scan; one thread per (b,d); y = (scan + u*Dskip) * silu(res)
__global__ __launch_bounds__(256)
void k_scan(const float* __restrict__ ur, const float* __restrict__ dbl,
            const float* __restrict__ delta, const float* __restrict__ A_log,
            const float* __restrict__ Dskip, float* __restrict__ y) {
    __shared__ float BC[SEQ][2 * DSTATE];
    int b  = blockIdx.x / (DINNER / 256);
    int dc = blockIdx.x % (DINNER / 256);
    int d  = dc * 256 + threadIdx.x;
    for (int t = threadIdx.x; t < SEQ * 2 * DSTATE; t += 256) {
        int v = t >> 5, s = t & 31;
        BC[v][s] = dbl[(size_t)(b * SEQ + v) * NDBL + DTRANK + s];
    }
    __syncthreads();
    float Arow[DSTATE];
    const float* ap = A_log + (size_t)d * DSTATE;
    #pragma unroll
    for (int s = 0; s < DSTATE; ++s) Arow[s] = -__expf(ap[s]);
    float dsk = Dskip[d];
    float st[DSTATE];
    #pragma unroll
    for (int s = 0; s < DSTATE; ++s) st[s] = 0.f;
    for (int v = 0; v < SEQ; ++v) {
        size_t mrow = (size_t)(b * SEQ + v);
        float dlt = delta[mrow * DINNER + d];
        float uu  = ur[mrow * NPROJ + d];
        float res = ur[mrow * NPROJ + DINNER + d];
        float du  = dlt * uu;
        float acc = 0.f;
        #pragma unroll
        for (int s = 0; s < DSTATE; ++s) {
            float dA = __expf(dlt * Arow[s]);
            st[s] = dA * st[s] + du * BC[v][s];
            acc += st[s] * BC[v][DSTATE + s];
        }
        float yv = acc + uu * dsk;
        y[mrow * DINNER + d] = yv * siluf(res);
    }
}

// final rmsnorm fused with reverse permutation: out[b,v] = rms(h[b,(v+vs[b])%SEQ])*w
__global__ __launch_bounds__(64)
void k_final(const float* __restrict__ h, const int* __restrict__ vs,
             const float* __restrict__ w, float* __restrict__ out) {
    int mv = blockIdx.x;
    int v = mv % SEQ, b = mv / SEQ;
    int src = (v + vs[b]) % SEQ;
    const float* row = h + (size_t)(b * SEQ + src) * DMODEL;
    int t = threadIdx.x;
    float ss = 0.f;
    for (int d = t; d < DMODEL; d += 64) { float x = row[d]; ss += x * x; }
    #pragma unroll
    for (int o = 32; o > 0; o >>= 1) ss += __shfl_xor(ss, o, 64);
    float sc = rsqrtf(ss / DMODEL + 1e-5f);
    float* op = out + (size_t)mv * DMODEL;
    for (int d = t; d < DMODEL; d += 64) op[d] = row[d] * sc * w[d];
}

extern "C" void kernel_launch(void* const* d_in, const int* in_sizes, int n_in,
                              void* d_out, int out_size, void* d_ws, size_t ws_size,
                              hipStream_t stream) {
    const float* x      = (const float*)d_in[0];
    const int*   vs     = (const int*)d_in[1];
    const float* norm_w = (const float*)d_in[2];
    const float* in_w   = (const float*)d_in[3];
    const float* conv_w = (const float*)d_in[4];
    const float* conv_b = (const float*)d_in[5];
    const float* xp_w   = (const float*)d_in[6];
    const float* dt_w   = (const float*)d_in[7];
    const float* dt_b   = (const float*)d_in[8];
    const float* A_log  = (const float*)d_in[9];
    const float* Dsk    = (const float*)d_in[10];
    const float* out_w  = (const float*)d_in[11];
    const float* nfw    = (const float*)d_in[12];
    float* out = (float*)d_out;

    float* ws    = (float*)d_ws;
    float* h     = ws;                                  // [MTOK, DMODEL]
    float* xn    = h     + (size_t)MTOK * DMODEL;       // [MTOK, DMODEL]
    float* ur    = xn    + (size_t)MTOK * DMODEL;       // [MTOK, NPROJ] (u | res)
    float* dbl   = ur    + (size_t)MTOK * NPROJ;        // [MTOK, NDBL]
    float* delta = dbl   + (size_t)MTOK * NDBL;         // [MTOK, DINNER]
    float* y     = delta + (size_t)MTOK * DINNER;       // [MTOK, DINNER]

    k_permute<<<(MTOK * DMODEL + 255) / 256, 256, 0, stream>>>(x, vs, h);

    for (int l = 0; l < NLAYER; ++l) {
        k_rmsnorm<<<MTOK, 64, 0, stream>>>(h, norm_w + (size_t)l * DMODEL, xn);

        k_gemm<<<dim3(NPROJ / 64, MTOK / 64), 256, 0, stream>>>(
            xn, DMODEL, in_w + (size_t)l * NPROJ * DMODEL, nullptr, ur, NPROJ, DMODEL);

        k_conv<<<(BATCH * DINNER + 255) / 256, 256, 0, stream>>>(
            ur, conv_w + (size_t)l * DINNER * DCONV, conv_b + (size_t)l * DINNER);

        k_gemm<<<dim3((NDBL + 63) / 64, MTOK / 64), 256, 0, stream>>>(
            ur, NPROJ, xp_w + (size_t)l * NDBL * DINNER, nullptr, dbl, NDBL, DINNER);

        k_dt<<<(MTOK * DINNER) / 256, 256, 0, stream>>>(
            dbl, dt_w + (size_t)l * DINNER * DTRANK, dt_b + (size_t)l * DINNER, delta);

        k_scan<<<BATCH * (DINNER / 256), 256, 0, stream>>>(
            ur, dbl, delta, A_log + (size_t)l * DINNER * DSTATE,
            Dsk + (size_t)l * DINNER, y);

        k_gemm<<<dim3(DMODEL / 64, MTOK / 64), 256, 0, stream>>>(
            y, DINNER, out_w + (size_t)l * DMODEL * DINNER, h, h, DMODEL, DINNER);
    }

    k_final<<<MTOK, 64, 0, stream>>>(h, vs, nfw, out);
}

// Round 2
// 947.520 us; speedup vs baseline: 1.4897x; 1.4897x over previous
//
#include <hip/hip_runtime.h>
#include <math.h>

#define NLAYER 4
#define DMODEL 640
#define DINNER 1280
#define DSTATE 16
#define DTRANK 40
#define DCONV  4
#define BATCH  64
#define SEQ    30
#define MTOK   (BATCH*SEQ)       // 1920
#define NPROJ  (2*DINNER)        // 2560
#define NDBL   (DTRANK+2*DSTATE) // 72

typedef unsigned short u16;
typedef __bf16 bf16x8 __attribute__((ext_vector_type(8)));
typedef float  f32x4  __attribute__((ext_vector_type(4)));

__device__ __forceinline__ float siluf(float x) {
    return x / (1.0f + __expf(-x));
}

// float -> bf16 bits, round-to-nearest-even (values are finite)
__device__ __forceinline__ u16 f2bf(float f) {
    unsigned int u = __float_as_uint(f);
    u += 0x7fffu + ((u >> 16) & 1u);
    return (u16)(u >> 16);
}

// h[b,v,:] = x[b,(v + SEQ - vs[b]) % SEQ, :]
__global__ void k_permute(const float* __restrict__ x, const int* __restrict__ vs,
                          float* __restrict__ h) {
    int idx = blockIdx.x * blockDim.x + threadIdx.x;
    if (idx >= MTOK * DMODEL) return;
    int d  = idx % DMODEL;
    int mv = idx / DMODEL;
    int v  = mv % SEQ;
    int b  = mv / SEQ;
    int src = (v + SEQ - vs[b]) % SEQ;
    h[idx] = x[(b * SEQ + src) * DMODEL + d];
}

// fp32 -> bf16 conversion, 4 elems/thread (n % 4 == 0)
__global__ void k_f2bf(const float* __restrict__ src, u16* __restrict__ dst, int n) {
    int i = (blockIdx.x * blockDim.x + threadIdx.x) * 4;
    if (i >= n) return;
    float4 v = *(const float4*)(src + i);
    ushort4 o;
    o.x = f2bf(v.x); o.y = f2bf(v.y); o.z = f2bf(v.z); o.w = f2bf(v.w);
    *(ushort4*)(dst + i) = o;
}

// one wave per token: xn_bf16 = h * rsqrt(mean(h^2)+eps) * w
__global__ __launch_bounds__(64)
void k_rmsnorm(const float* __restrict__ h, const float* __restrict__ w,
               u16* __restrict__ xn) {
    int m = blockIdx.x;
    int t = threadIdx.x;
    const float* row = h + (size_t)m * DMODEL;
    float ss = 0.f;
    for (int d = t; d < DMODEL; d += 64) { float v = row[d]; ss += v * v; }
    #pragma unroll
    for (int o = 32; o > 0; o >>= 1) ss += __shfl_xor(ss, o, 64);
    float sc = rsqrtf(ss / DMODEL + 1e-5f);
    u16* out = xn + (size_t)m * DMODEL;
    for (int d = t; d < DMODEL; d += 64) out[d] = f2bf(row[d] * sc * w[d]);
}

// bf16 MFMA GEMM (m97 structure): C[m,n] = sum_k A[m,k]*W[n,k] (+resid)
// A: bf16 [M,lda], W: bf16 [N,K], C: f32 [M,N]. M,N mult of 128, K mult of 32.
// 256 thr = 4 waves in 2x2; wave computes 64x64 via 4x4 16x16x32 MFMA tiles.
__global__ __launch_bounds__(256)
void k_mfma(const u16* __restrict__ A, int lda,
            const u16* __restrict__ W,
            const float* __restrict__ resid,
            float* __restrict__ C, int N, int K) {
    __shared__ u16 As[128 * 32];
    __shared__ u16 Bs[128 * 32];
    const int t = threadIdx.x;
    const int w = t >> 6, l = t & 63;
    const int lane15 = l & 15, quad = l >> 4;
    const int wm = w >> 1, wn = w & 1;
    const int m0 = blockIdx.y * 128, n0 = blockIdx.x * 128;

    f32x4 acc[4][4];
    #pragma unroll
    for (int i = 0; i < 4; ++i)
        #pragma unroll
        for (int j = 0; j < 4; ++j)
            acc[i][j] = (f32x4){0.f, 0.f, 0.f, 0.f};

    for (int k0 = 0; k0 < K; k0 += 32) {
        __syncthreads();   // protect LDS from previous iter's readers
        // stage A-tile (128x32 bf16 = 8KB) and B-tile via global_load_lds x16B
        #pragma unroll
        for (int q = 0; q < 2; ++q) {
            int c = q * 256 + t;                  // 16B-chunk id, 0..511
            const u16* ga = A + (size_t)(m0 + (c >> 2)) * lda + k0 + (c & 3) * 8;
            __builtin_amdgcn_global_load_lds(
                (const __attribute__((address_space(1))) void*)ga,
                (__attribute__((address_space(3))) void*)&As[c * 8], 16, 0, 0);
            const u16* gb = W + (size_t)(n0 + (c >> 2)) * K + k0 + (c & 3) * 8;
            __builtin_amdgcn_global_load_lds(
                (const __attribute__((address_space(1))) void*)gb,
                (__attribute__((address_space(3))) void*)&Bs[c * 8], 16, 0, 0);
        }
        __syncthreads();   // drains vmcnt(0)

        bf16x8 af[4], bfrag[4];
        #pragma unroll
        for (int i = 0; i < 4; ++i)
            af[i] = *(const bf16x8*)&As[(wm * 64 + i * 16 + lane15) * 32 + quad * 8];
        #pragma unroll
        for (int j = 0; j < 4; ++j)
            bfrag[j] = *(const bf16x8*)&Bs[(wn * 64 + j * 16 + lane15) * 32 + quad * 8];
        #pragma unroll
        for (int i = 0; i < 4; ++i)
            #pragma unroll
            for (int j = 0; j < 4; ++j)
                acc[i][j] = __builtin_amdgcn_mfma_f32_16x16x32_bf16(
                    af[i], bfrag[j], acc[i][j], 0, 0, 0);
    }

    // epilogue: C/D layout col=lane&15, row=quad*4+r
    #pragma unroll
    for (int i = 0; i < 4; ++i) {
        #pragma unroll
        for (int r = 0; r < 4; ++r) {
            int row = m0 + wm * 64 + i * 16 + quad * 4 + r;
            #pragma unroll
            for (int j = 0; j < 4; ++j) {
                int col = n0 + wn * 64 + j * 16 + lane15;
                size_t idx = (size_t)row * N + col;
                float v = acc[i][j][r];
                if (resid) v += resid[idx];
                C[idx] = v;
            }
        }
    }
}

// fp32 tiled GEMM (kept for skinny x_proj): C[m,n] = sum_k A[m,lda]*W[n,k]
__global__ __launch_bounds__(256)
void k_gemm(const float* __restrict__ A, int lda,
            const float* __restrict__ W,
            float* __restrict__ C, int N, int K) {
    __shared__ float As[16][64];
    __shared__ float Bs[16][64];
    int t  = threadIdx.x;
    int tx = t & 15, ty = t >> 4;
    int m0 = blockIdx.y * 64, n0 = blockIdx.x * 64;
    int lrow = t >> 2;
    int lk   = (t & 3) * 4;
    float c[4][4] = {{0.f}};
    for (int k0 = 0; k0 < K; k0 += 16) {
        float4 a4 = *(const float4*)(A + (size_t)(m0 + lrow) * lda + k0 + lk);
        float4 b4 = make_float4(0.f, 0.f, 0.f, 0.f);
        if (n0 + lrow < N)
            b4 = *(const float4*)(W + (size_t)(n0 + lrow) * K + k0 + lk);
        __syncthreads();
        As[lk + 0][lrow] = a4.x; As[lk + 1][lrow] = a4.y;
        As[lk + 2][lrow] = a4.z; As[lk + 3][lrow] = a4.w;
        Bs[lk + 0][lrow] = b4.x; Bs[lk + 1][lrow] = b4.y;
        Bs[lk + 2][lrow] = b4.z; Bs[lk + 3][lrow] = b4.w;
        __syncthreads();
        #pragma unroll
        for (int kk = 0; kk < 16; ++kk) {
            float4 av = *(const float4*)&As[kk][ty * 4];
            float4 bv = *(const float4*)&Bs[kk][tx * 4];
            c[0][0] += av.x * bv.x; c[0][1] += av.x * bv.y;
            c[0][2] += av.x * bv.z; c[0][3] += av.x * bv.w;
            c[1][0] += av.y * bv.x; c[1][1] += av.y * bv.y;
            c[1][2] += av.y * bv.z; c[1][3] += av.y * bv.w;
            c[2][0] += av.z * bv.x; c[2][1] += av.z * bv.y;
            c[2][2] += av.z * bv.z; c[2][3] += av.z * bv.w;
            c[3][0] += av.w * bv.x; c[3][1] += av.w * bv.y;
            c[3][2] += av.w * bv.z; c[3][3] += av.w * bv.w;
        }
    }
    #pragma unroll
    for (int i = 0; i < 4; ++i) {
        int m = m0 + ty * 4 + i;
        int n = n0 + tx * 4;
        for (int j = 0; j < 4; ++j)
            if (n + j < N) C[(size_t)m * N + n + j] = c[i][j];
    }
}

// causal depthwise conv over v, in place on the u half of ur, + bias, silu
__global__ void k_conv(float* __restrict__ ur, const float* __restrict__ cw,
                       const float* __restrict__ cb) {
    int idx = blockIdx.x * blockDim.x + threadIdx.x;
    if (idx >= BATCH * DINNER) return;
    int c = idx % DINNER;
    int b = idx / DINNER;
    float w0 = cw[c * 4 + 0], w1 = cw[c * 4 + 1], w2 = cw[c * 4 + 2], w3 = cw[c * 4 + 3];
    float bias = cb[c];
    float* base = ur + (size_t)(b * SEQ) * NPROJ + c;
    float x0 = 0.f, x1 = 0.f, x2 = 0.f;
    for (int v = 0; v < SEQ; ++v) {
        float x3 = base[(size_t)v * NPROJ];
        float o = bias + w0 * x0 + w1 * x1 + w2 * x2 + w3 * x3;
        base[(size_t)v * NPROJ] = siluf(o);
        x0 = x1; x1 = x2; x2 = x3;
    }
}

// delta[m,d] = softplus(sum_r dbl[m,r]*dtw[d,r] + dtb[d])
__global__ __launch_bounds__(256)
void k_dt(const float* __restrict__ dbl, const float* __restrict__ dtw,
          const float* __restrict__ dtb, float* __restrict__ delta) {
    __shared__ float row[DTRANK];
    int idx = blockIdx.x * 256 + threadIdx.x;
    int m = idx / DINNER;
    int d = idx % DINNER;
    if (threadIdx.x < DTRANK) row[threadIdx.x] = dbl[(size_t)m * NDBL + threadIdx.x];
    __syncthreads();
    float acc = dtb[d];
    const float* wp = dtw + (size_t)d * DTRANK;
    #pragma unroll
    for (int r = 0; r < DTRANK; ++r) acc += row[r] * wp[r];
    delta[idx] = (acc > 20.f) ? acc : log1pf(__expf(acc));
}

// selective scan; one thread per (b,d); y_bf16 = ((scan + u*Dskip) * silu(res))
__global__ __launch_bounds__(256)
void k_scan(const float* __restrict__ ur, const float* __restrict__ dbl,
            const float* __restrict__ delta, const float* __restrict__ A_log,
            const float* __restrict__ Dskip, u16* __restrict__ y) {
    __shared__ float BC[SEQ][2 * DSTATE];
    int b  = blockIdx.x / (DINNER / 256);
    int dc = blockIdx.x % (DINNER / 256);
    int d  = dc * 256 + threadIdx.x;
    for (int t = threadIdx.x; t < SEQ * 2 * DSTATE; t += 256) {
        int v = t >> 5, s = t & 31;
        BC[v][s] = dbl[(size_t)(b * SEQ + v) * NDBL + DTRANK + s];
    }
    __syncthreads();
    float Arow[DSTATE];
    const float* ap = A_log + (size_t)d * DSTATE;
    #pragma unroll
    for (int s = 0; s < DSTATE; ++s) Arow[s] = -__expf(ap[s]);
    float dsk = Dskip[d];
    float st[DSTATE];
    #pragma unroll
    for (int s = 0; s < DSTATE; ++s) st[s] = 0.f;
    for (int v = 0; v < SEQ; ++v) {
        size_t mrow = (size_t)(b * SEQ + v);
        float dlt = delta[mrow * DINNER + d];
        float uu  = ur[mrow * NPROJ + d];
        float res = ur[mrow * NPROJ + DINNER + d];
        float du  = dlt * uu;
        float acc = 0.f;
        #pragma unroll
        for (int s = 0; s < DSTATE; ++s) {
            float dA = __expf(dlt * Arow[s]);
            st[s] = dA * st[s] + du * BC[v][s];
            acc += st[s] * BC[v][DSTATE + s];
        }
        float yv = acc + uu * dsk;
        y[mrow * DINNER + d] = f2bf(yv * siluf(res));
    }
}

// final rmsnorm fused with reverse permutation
__global__ __launch_bounds__(64)
void k_final(const float* __restrict__ h, const int* __restrict__ vs,
             const float* __restrict__ w, float* __restrict__ out) {
    int mv = blockIdx.x;
    int v = mv % SEQ, b = mv / SEQ;
    int src = (v + vs[b]) % SEQ;
    const float* row = h + (size_t)(b * SEQ + src) * DMODEL;
    int t = threadIdx.x;
    float ss = 0.f;
    for (int d = t; d < DMODEL; d += 64) { float x = row[d]; ss += x * x; }
    #pragma unroll
    for (int o = 32; o > 0; o >>= 1) ss += __shfl_xor(ss, o, 64);
    float sc = rsqrtf(ss / DMODEL + 1e-5f);
    float* op = out + (size_t)mv * DMODEL;
    for (int d = t; d < DMODEL; d += 64) op[d] = row[d] * sc * w[d];
}

extern "C" void kernel_launch(void* const* d_in, const int* in_sizes, int n_in,
                              void* d_out, int out_size, void* d_ws, size_t ws_size,
                              hipStream_t stream) {
    const float* x      = (const float*)d_in[0];
    const int*   vs     = (const int*)d_in[1];
    const float* norm_w = (const float*)d_in[2];
    const float* in_w   = (const float*)d_in[3];
    const float* conv_w = (const float*)d_in[4];
    const float* conv_b = (const float*)d_in[5];
    const float* xp_w   = (const float*)d_in[6];
    const float* dt_w   = (const float*)d_in[7];
    const float* dt_b   = (const float*)d_in[8];
    const float* A_log  = (const float*)d_in[9];
    const float* Dsk    = (const float*)d_in[10];
    const float* out_w  = (const float*)d_in[11];
    const float* nfw    = (const float*)d_in[12];
    float* out = (float*)d_out;

    char* p = (char*)d_ws;
    float* h     = (float*)p; p += (size_t)MTOK * DMODEL * 4;
    u16*   xn    = (u16*)p;   p += (size_t)MTOK * DMODEL * 2;
    float* ur    = (float*)p; p += (size_t)MTOK * NPROJ * 4;
    float* dbl   = (float*)p; p += (size_t)MTOK * NDBL * 4;
    float* delta = (float*)p; p += (size_t)MTOK * DINNER * 4;
    u16*   y     = (u16*)p;   p += (size_t)MTOK * DINNER * 2;
    u16*   wbi   = (u16*)p;   p += (size_t)NPROJ * DMODEL * 2;
    u16*   wbo   = (u16*)p;   p += (size_t)DMODEL * DINNER * 2;

    k_permute<<<(MTOK * DMODEL + 255) / 256, 256, 0, stream>>>(x, vs, h);

    for (int l = 0; l < NLAYER; ++l) {
        k_f2bf<<<(NPROJ * DMODEL / 4 + 255) / 256, 256, 0, stream>>>(
            in_w + (size_t)l * NPROJ * DMODEL, wbi, NPROJ * DMODEL);
        k_f2bf<<<(DMODEL * DINNER / 4 + 255) / 256, 256, 0, stream>>>(
            out_w + (size_t)l * DMODEL * DINNER, wbo, DMODEL * DINNER);

        k_rmsnorm<<<MTOK, 64, 0, stream>>>(h, norm_w + (size_t)l * DMODEL, xn);

        k_mfma<<<dim3(NPROJ / 128, MTOK / 128), 256, 0, stream>>>(
            xn, DMODEL, wbi, nullptr, ur, NPROJ, DMODEL);

        k_conv<<<(BATCH * DINNER + 255) / 256, 256, 0, stream>>>(
            ur, conv_w + (size_t)l * DINNER * DCONV, conv_b + (size_t)l * DINNER);

        k_gemm<<<dim3((NDBL + 63) / 64, MTOK / 64), 256, 0, stream>>>(
            ur, NPROJ, xp_w + (size_t)l * NDBL * DINNER, dbl, NDBL, DINNER);

        k_dt<<<(MTOK * DINNER) / 256, 256, 0, stream>>>(
            dbl, dt_w + (size_t)l * DINNER * DTRANK, dt_b + (size_t)l * DINNER, delta);

        k_scan<<<BATCH * (DINNER / 256), 256, 0, stream>>>(
            ur, dbl, delta, A_log + (size_t)l * DINNER * DSTATE,
            Dsk + (size_t)l * DINNER, y);

        k_mfma<<<dim3(DMODEL / 128, MTOK / 128), 256, 0, stream>>>(
            y, DINNER, wbo, h, h, DMODEL, DINNER);
    }

    k_final<<<MTOK, 64, 0, stream>>>(h, vs, nfw, out);
}

// Round 3
// 623.690 us; speedup vs baseline: 2.2632x; 1.5192x over previous
//
#include <hip/hip_runtime.h>
#include <math.h>

#define NLAYER 4
#define DMODEL 640
#define DINNER 1280
#define DSTATE 16
#define DTRANK 40
#define DCONV  4
#define BATCH  64
#define SEQ    30
#define MTOK   (BATCH*SEQ)       // 1920
#define NPROJ  (2*DINNER)        // 2560
#define NDBL   (DTRANK+2*DSTATE) // 72
#define NDBLP  80                // padded N for x_proj MFMA
#define KSEGS  4
#define KSEG   (DINNER/KSEGS)    // 320

typedef unsigned short u16;
typedef __bf16 bf16x8 __attribute__((ext_vector_type(8)));
typedef float  f32x4  __attribute__((ext_vector_type(4)));

__device__ __forceinline__ float siluf(float x) {
    return x / (1.0f + __expf(-x));
}

__device__ __forceinline__ u16 f2bf(float f) {
    unsigned int u = __float_as_uint(f);
    u += 0x7fffu + ((u >> 16) & 1u);
    return (u16)(u >> 16);
}

// h[b,v,:] = x[b,(v + SEQ - vs[b]) % SEQ, :]
__global__ void k_permute(const float* __restrict__ x, const int* __restrict__ vs,
                          float* __restrict__ h) {
    int idx = blockIdx.x * blockDim.x + threadIdx.x;
    if (idx >= MTOK * DMODEL) return;
    int d  = idx % DMODEL;
    int mv = idx / DMODEL;
    int v  = mv % SEQ;
    int b  = mv / SEQ;
    int src = (v + SEQ - vs[b]) % SEQ;
    h[idx] = x[(b * SEQ + src) * DMODEL + d];
}

// fp32 -> bf16, 4/thread
__global__ void k_f2bf(const float* __restrict__ src, u16* __restrict__ dst, int n) {
    int i = (blockIdx.x * blockDim.x + threadIdx.x) * 4;
    if (i >= n) return;
    float4 v = *(const float4*)(src + i);
    ushort4 o;
    o.x = f2bf(v.x); o.y = f2bf(v.y); o.z = f2bf(v.z); o.w = f2bf(v.w);
    *(ushort4*)(dst + i) = o;
}

// xp_w [72,1280] fp32 -> [80,1280] bf16, rows 72..79 zeroed
__global__ void k_f2bf_pad(const float* __restrict__ src, u16* __restrict__ dst) {
    int i = (blockIdx.x * blockDim.x + threadIdx.x) * 4;
    if (i >= NDBLP * DINNER) return;
    int row = i / DINNER;
    ushort4 o = make_ushort4(0, 0, 0, 0);
    if (row < NDBL) {
        float4 v = *(const float4*)(src + i - (row * DINNER - row * DINNER)); // same idx
        v = *(const float4*)(src + (size_t)row * DINNER + (i % DINNER));
        o.x = f2bf(v.x); o.y = f2bf(v.y); o.z = f2bf(v.z); o.w = f2bf(v.w);
    }
    *(ushort4*)(dst + i) = o;
}

// one wave per token: xn_bf16 = h * rsqrt(mean(h^2)+eps) * w
__global__ __launch_bounds__(64)
void k_rmsnorm(const float* __restrict__ h, const float* __restrict__ w,
               u16* __restrict__ xn) {
    int m = blockIdx.x;
    int t = threadIdx.x;
    const float* row = h + (size_t)m * DMODEL;
    float ss = 0.f;
    for (int d = t; d < DMODEL; d += 64) { float v = row[d]; ss += v * v; }
    #pragma unroll
    for (int o = 32; o > 0; o >>= 1) ss += __shfl_xor(ss, o, 64);
    float sc = rsqrtf(ss / DMODEL + 1e-5f);
    u16* out = xn + (size_t)m * DMODEL;
    for (int d = t; d < DMODEL; d += 64) out[d] = f2bf(row[d] * sc * w[d]);
}

// 128x128-tile bf16 MFMA GEMM: C[m,n] = sum_k A[m,k]*W[n,k] (+resid)
__global__ __launch_bounds__(256)
void k_mfma(const u16* __restrict__ A, int lda,
            const u16* __restrict__ W,
            const float* __restrict__ resid,
            float* __restrict__ C, int N, int K) {
    __shared__ u16 As[128 * 32];
    __shared__ u16 Bs[128 * 32];
    const int t = threadIdx.x;
    const int w = t >> 6, l = t & 63;
    const int lane15 = l & 15, quad = l >> 4;
    const int wm = w >> 1, wn = w & 1;
    const int m0 = blockIdx.y * 128, n0 = blockIdx.x * 128;

    f32x4 acc[4][4];
    #pragma unroll
    for (int i = 0; i < 4; ++i)
        #pragma unroll
        for (int j = 0; j < 4; ++j)
            acc[i][j] = (f32x4){0.f, 0.f, 0.f, 0.f};

    for (int k0 = 0; k0 < K; k0 += 32) {
        __syncthreads();
        #pragma unroll
        for (int q = 0; q < 2; ++q) {
            int c = q * 256 + t;
            const u16* ga = A + (size_t)(m0 + (c >> 2)) * lda + k0 + (c & 3) * 8;
            __builtin_amdgcn_global_load_lds(
                (const __attribute__((address_space(1))) void*)ga,
                (__attribute__((address_space(3))) void*)&As[c * 8], 16, 0, 0);
            const u16* gb = W + (size_t)(n0 + (c >> 2)) * K + k0 + (c & 3) * 8;
            __builtin_amdgcn_global_load_lds(
                (const __attribute__((address_space(1))) void*)gb,
                (__attribute__((address_space(3))) void*)&Bs[c * 8], 16, 0, 0);
        }
        __syncthreads();

        bf16x8 af[4], bfrag[4];
        #pragma unroll
        for (int i = 0; i < 4; ++i)
            af[i] = *(const bf16x8*)&As[(wm * 64 + i * 16 + lane15) * 32 + quad * 8];
        #pragma unroll
        for (int j = 0; j < 4; ++j)
            bfrag[j] = *(const bf16x8*)&Bs[(wn * 64 + j * 16 + lane15) * 32 + quad * 8];
        #pragma unroll
        for (int i = 0; i < 4; ++i)
            #pragma unroll
            for (int j = 0; j < 4; ++j)
                acc[i][j] = __builtin_amdgcn_mfma_f32_16x16x32_bf16(
                    af[i], bfrag[j], acc[i][j], 0, 0, 0);
    }

    #pragma unroll
    for (int i = 0; i < 4; ++i) {
        #pragma unroll
        for (int r = 0; r < 4; ++r) {
            int row = m0 + wm * 64 + i * 16 + quad * 4 + r;
            #pragma unroll
            for (int j = 0; j < 4; ++j) {
                int col = n0 + wn * 64 + j * 16 + lane15;
                size_t idx = (size_t)row * N + col;
                float v = acc[i][j][r];
                if (resid) v += resid[idx];
                C[idx] = v;
            }
        }
    }
}

// 64x64-tile bf16 MFMA GEMM (better occupancy for narrow N)
__global__ __launch_bounds__(256)
void k_mfma64(const u16* __restrict__ A, int lda,
              const u16* __restrict__ W,
              const float* __restrict__ resid,
              float* __restrict__ C, int N, int K) {
    __shared__ u16 As[64 * 32];
    __shared__ u16 Bs[64 * 32];
    const int t = threadIdx.x;
    const int w = t >> 6, l = t & 63;
    const int lane15 = l & 15, quad = l >> 4;
    const int wm = w >> 1, wn = w & 1;
    const int m0 = blockIdx.y * 64, n0 = blockIdx.x * 64;

    f32x4 acc[2][2];
    #pragma unroll
    for (int i = 0; i < 2; ++i)
        #pragma unroll
        for (int j = 0; j < 2; ++j)
            acc[i][j] = (f32x4){0.f, 0.f, 0.f, 0.f};

    for (int k0 = 0; k0 < K; k0 += 32) {
        __syncthreads();
        {
            int c = t;  // 256 chunks of 16B cover 64x32 bf16
            const u16* ga = A + (size_t)(m0 + (c >> 2)) * lda + k0 + (c & 3) * 8;
            __builtin_amdgcn_global_load_lds(
                (const __attribute__((address_space(1))) void*)ga,
                (__attribute__((address_space(3))) void*)&As[c * 8], 16, 0, 0);
            const u16* gb = W + (size_t)(n0 + (c >> 2)) * K + k0 + (c & 3) * 8;
            __builtin_amdgcn_global_load_lds(
                (const __attribute__((address_space(1))) void*)gb,
                (__attribute__((address_space(3))) void*)&Bs[c * 8], 16, 0, 0);
        }
        __syncthreads();

        bf16x8 af[2], bfrag[2];
        #pragma unroll
        for (int i = 0; i < 2; ++i)
            af[i] = *(const bf16x8*)&As[(wm * 32 + i * 16 + lane15) * 32 + quad * 8];
        #pragma unroll
        for (int j = 0; j < 2; ++j)
            bfrag[j] = *(const bf16x8*)&Bs[(wn * 32 + j * 16 + lane15) * 32 + quad * 8];
        #pragma unroll
        for (int i = 0; i < 2; ++i)
            #pragma unroll
            for (int j = 0; j < 2; ++j)
                acc[i][j] = __builtin_amdgcn_mfma_f32_16x16x32_bf16(
                    af[i], bfrag[j], acc[i][j], 0, 0, 0);
    }

    #pragma unroll
    for (int i = 0; i < 2; ++i) {
        #pragma unroll
        for (int r = 0; r < 4; ++r) {
            int row = m0 + wm * 32 + i * 16 + quad * 4 + r;
            #pragma unroll
            for (int j = 0; j < 2; ++j) {
                int col = n0 + wn * 32 + j * 16 + lane15;
                size_t idx = (size_t)row * N + col;
                float v = acc[i][j][r];
                if (resid) v += resid[idx];
                C[idx] = v;
            }
        }
    }
}

// x_proj: split-K bf16 MFMA. A=ubf [MTOK,DINNER], B=wbx [80,DINNER].
// Block: 64 M-rows x 80 N x 320 K-seg. Grid (KSEGS, MTOK/64). 4 waves, each
// wave = one 16-row tile x 5 N-tiles. Writes fp32 partial dblp[seg][MTOK][80].
__global__ __launch_bounds__(256)
void k_xproj(const u16* __restrict__ ubf, const u16* __restrict__ wbx,
             float* __restrict__ dblp) {
    __shared__ u16 As[64 * 32];
    __shared__ u16 Bs[NDBLP * 32];
    const int t = threadIdx.x;
    const int w = t >> 6, l = t & 63;
    const int lane15 = l & 15, quad = l >> 4;
    const int seg = blockIdx.x;
    const int m0 = blockIdx.y * 64;
    const int kb = seg * KSEG;

    f32x4 acc[5];
    #pragma unroll
    for (int j = 0; j < 5; ++j) acc[j] = (f32x4){0.f, 0.f, 0.f, 0.f};

    for (int k0 = 0; k0 < KSEG; k0 += 32) {
        __syncthreads();
        {
            int c = t;  // A: 64 rows x 4 16B-chunks = 256
            const u16* ga = ubf + (size_t)(m0 + (c >> 2)) * DINNER + kb + k0 + (c & 3) * 8;
            __builtin_amdgcn_global_load_lds(
                (const __attribute__((address_space(1))) void*)ga,
                (__attribute__((address_space(3))) void*)&As[c * 8], 16, 0, 0);
            const u16* gb = wbx + (size_t)(c >> 2) * DINNER + kb + k0 + (c & 3) * 8;
            __builtin_amdgcn_global_load_lds(
                (const __attribute__((address_space(1))) void*)gb,
                (__attribute__((address_space(3))) void*)&Bs[c * 8], 16, 0, 0);
        }
        if (t < 64) {  // B rows 64..79: 64 more chunks (wave 0 only)
            int c = 256 + t;
            const u16* gb = wbx + (size_t)(c >> 2) * DINNER + kb + k0 + (c & 3) * 8;
            __builtin_amdgcn_global_load_lds(
                (const __attribute__((address_space(1))) void*)gb,
                (__attribute__((address_space(3))) void*)&Bs[c * 8], 16, 0, 0);
        }
        __syncthreads();

        bf16x8 af = *(const bf16x8*)&As[(w * 16 + lane15) * 32 + quad * 8];
        #pragma unroll
        for (int j = 0; j < 5; ++j) {
            bf16x8 bfrag = *(const bf16x8*)&Bs[(j * 16 + lane15) * 32 + quad * 8];
            acc[j] = __builtin_amdgcn_mfma_f32_16x16x32_bf16(af, bfrag, acc[j], 0, 0, 0);
        }
    }

    float* outp = dblp + (size_t)seg * MTOK * NDBLP;
    #pragma unroll
    for (int r = 0; r < 4; ++r) {
        int row = m0 + w * 16 + quad * 4 + r;
        #pragma unroll
        for (int j = 0; j < 5; ++j) {
            int col = j * 16 + lane15;
            outp[(size_t)row * NDBLP + col] = acc[j][r];
        }
    }
}

// causal depthwise conv over v, in place on u half of ur; also emits bf16 u
__global__ void k_conv(float* __restrict__ ur, const float* __restrict__ cw,
                       const float* __restrict__ cb, u16* __restrict__ ubf) {
    int idx = blockIdx.x * blockDim.x + threadIdx.x;
    if (idx >= BATCH * DINNER) return;
    int c = idx % DINNER;
    int b = idx / DINNER;
    float w0 = cw[c * 4 + 0], w1 = cw[c * 4 + 1], w2 = cw[c * 4 + 2], w3 = cw[c * 4 + 3];
    float bias = cb[c];
    float* base = ur + (size_t)(b * SEQ) * NPROJ + c;
    u16* ubase = ubf + (size_t)(b * SEQ) * DINNER + c;
    float x0 = 0.f, x1 = 0.f, x2 = 0.f;
    for (int v = 0; v < SEQ; ++v) {
        float x3 = base[(size_t)v * NPROJ];
        float o = bias + w0 * x0 + w1 * x1 + w2 * x2 + w3 * x3;
        float s = siluf(o);
        base[(size_t)v * NPROJ] = s;
        ubase[(size_t)v * DINNER] = f2bf(s);
        x0 = x1; x1 = x2; x2 = x3;
    }
}

// delta[m,d] = softplus(sum_r (sum_s dblp[s][m][r]) * dtw[d,r] + dtb[d])
__global__ __launch_bounds__(256)
void k_dt(const float* __restrict__ dblp, const float* __restrict__ dtw,
          const float* __restrict__ dtb, float* __restrict__ delta) {
    __shared__ float row[DTRANK];
    int idx = blockIdx.x * 256 + threadIdx.x;
    int m = idx / DINNER;
    int d = idx % DINNER;
    if (threadIdx.x < DTRANK) {
        float s = 0.f;
        #pragma unroll
        for (int sg = 0; sg < KSEGS; ++sg)
            s += dblp[(size_t)sg * MTOK * NDBLP + (size_t)m * NDBLP + threadIdx.x];
        row[threadIdx.x] = s;
    }
    __syncthreads();
    float acc = dtb[d];
    const float* wp = dtw + (size_t)d * DTRANK;
    #pragma unroll
    for (int r = 0; r < DTRANK; ++r) acc += row[r] * wp[r];
    delta[idx] = (acc > 20.f) ? acc : log1pf(__expf(acc));
}

// selective scan; one thread per (b,d)
__global__ __launch_bounds__(256)
void k_scan(const float* __restrict__ ur, const float* __restrict__ dblp,
            const float* __restrict__ delta, const float* __restrict__ A_log,
            const float* __restrict__ Dskip, u16* __restrict__ y) {
    __shared__ float BC[SEQ][2 * DSTATE];
    int b  = blockIdx.x / (DINNER / 256);
    int dc = blockIdx.x % (DINNER / 256);
    int d  = dc * 256 + threadIdx.x;
    for (int t = threadIdx.x; t < SEQ * 2 * DSTATE; t += 256) {
        int v = t >> 5, s = t & 31;
        float acc = 0.f;
        #pragma unroll
        for (int sg = 0; sg < KSEGS; ++sg)
            acc += dblp[(size_t)sg * MTOK * NDBLP + (size_t)(b * SEQ + v) * NDBLP + DTRANK + s];
        BC[v][s] = acc;
    }
    __syncthreads();
    float Arow[DSTATE];
    const float* ap = A_log + (size_t)d * DSTATE;
    #pragma unroll
    for (int s = 0; s < DSTATE; ++s) Arow[s] = -__expf(ap[s]);
    float dsk = Dskip[d];
    float st[DSTATE];
    #pragma unroll
    for (int s = 0; s < DSTATE; ++s) st[s] = 0.f;
    for (int v = 0; v < SEQ; ++v) {
        size_t mrow = (size_t)(b * SEQ + v);
        float dlt = delta[mrow * DINNER + d];
        float uu  = ur[mrow * NPROJ + d];
        float res = ur[mrow * NPROJ + DINNER + d];
        float du  = dlt * uu;
        float acc = 0.f;
        #pragma unroll
        for (int s = 0; s < DSTATE; ++s) {
            float dA = __expf(dlt * Arow[s]);
            st[s] = dA * st[s] + du * BC[v][s];
            acc += st[s] * BC[v][DSTATE + s];
        }
        float yv = acc + uu * dsk;
        y[mrow * DINNER + d] = f2bf(yv * siluf(res));
    }
}

// final rmsnorm fused with reverse permutation
__global__ __launch_bounds__(64)
void k_final(const float* __restrict__ h, const int* __restrict__ vs,
             const float* __restrict__ w, float* __restrict__ out) {
    int mv = blockIdx.x;
    int v = mv % SEQ, b = mv / SEQ;
    int src = (v + vs[b]) % SEQ;
    const float* row = h + (size_t)(b * SEQ + src) * DMODEL;
    int t = threadIdx.x;
    float ss = 0.f;
    for (int d = t; d < DMODEL; d += 64) { float x = row[d]; ss += x * x; }
    #pragma unroll
    for (int o = 32; o > 0; o >>= 1) ss += __shfl_xor(ss, o, 64);
    float sc = rsqrtf(ss / DMODEL + 1e-5f);
    float* op = out + (size_t)mv * DMODEL;
    for (int d = t; d < DMODEL; d += 64) op[d] = row[d] * sc * w[d];
}

extern "C" void kernel_launch(void* const* d_in, const int* in_sizes, int n_in,
                              void* d_out, int out_size, void* d_ws, size_t ws_size,
                              hipStream_t stream) {
    const float* x      = (const float*)d_in[0];
    const int*   vs     = (const int*)d_in[1];
    const float* norm_w = (const float*)d_in[2];
    const float* in_w   = (const float*)d_in[3];
    const float* conv_w = (const float*)d_in[4];
    const float* conv_b = (const float*)d_in[5];
    const float* xp_w   = (const float*)d_in[6];
    const float* dt_w   = (const float*)d_in[7];
    const float* dt_b   = (const float*)d_in[8];
    const float* A_log  = (const float*)d_in[9];
    const float* Dsk    = (const float*)d_in[10];
    const float* out_w  = (const float*)d_in[11];
    const float* nfw    = (const float*)d_in[12];
    float* out = (float*)d_out;

    char* p = (char*)d_ws;
    float* h     = (float*)p; p += (size_t)MTOK * DMODEL * 4;
    u16*   xn    = (u16*)p;   p += (size_t)MTOK * DMODEL * 2;
    float* ur    = (float*)p; p += (size_t)MTOK * NPROJ * 4;
    u16*   ubf   = (u16*)p;   p += (size_t)MTOK * DINNER * 2;
    float* dblp  = (float*)p; p += (size_t)KSEGS * MTOK * NDBLP * 4;
    float* delta = (float*)p; p += (size_t)MTOK * DINNER * 4;
    u16*   y     = (u16*)p;   p += (size_t)MTOK * DINNER * 2;
    u16*   wbi   = (u16*)p;   p += (size_t)NPROJ * DMODEL * 2;
    u16*   wbo   = (u16*)p;   p += (size_t)DMODEL * DINNER * 2;
    u16*   wbx   = (u16*)p;   p += (size_t)NDBLP * DINNER * 2;

    k_permute<<<(MTOK * DMODEL + 255) / 256, 256, 0, stream>>>(x, vs, h);

    for (int l = 0; l < NLAYER; ++l) {
        k_f2bf<<<(NPROJ * DMODEL / 4 + 255) / 256, 256, 0, stream>>>(
            in_w + (size_t)l * NPROJ * DMODEL, wbi, NPROJ * DMODEL);
        k_f2bf<<<(DMODEL * DINNER / 4 + 255) / 256, 256, 0, stream>>>(
            out_w + (size_t)l * DMODEL * DINNER, wbo, DMODEL * DINNER);
        k_f2bf_pad<<<(NDBLP * DINNER / 4 + 255) / 256, 256, 0, stream>>>(
            xp_w + (size_t)l * NDBL * DINNER, wbx);

        k_rmsnorm<<<MTOK, 64, 0, stream>>>(h, norm_w + (size_t)l * DMODEL, xn);

        k_mfma<<<dim3(NPROJ / 128, MTOK / 128), 256, 0, stream>>>(
            xn, DMODEL, wbi, nullptr, ur, NPROJ, DMODEL);

        k_conv<<<(BATCH * DINNER + 255) / 256, 256, 0, stream>>>(
            ur, conv_w + (size_t)l * DINNER * DCONV, conv_b + (size_t)l * DINNER, ubf);

        k_xproj<<<dim3(KSEGS, MTOK / 64), 256, 0, stream>>>(ubf, wbx, dblp);

        k_dt<<<(MTOK * DINNER) / 256, 256, 0, stream>>>(
            dblp, dt_w + (size_t)l * DINNER * DTRANK, dt_b + (size_t)l * DINNER, delta);

        k_scan<<<BATCH * (DINNER / 256), 256, 0, stream>>>(
            ur, dblp, delta, A_log + (size_t)l * DINNER * DSTATE,
            Dsk + (size_t)l * DINNER, y);

        k_mfma64<<<dim3(DMODEL / 64, MTOK / 64), 256, 0, stream>>>(
            y, DINNER, wbo, h, h, DMODEL, DINNER);
    }

    k_final<<<MTOK, 64, 0, stream>>>(h, vs, nfw, out);
}